// Round 1
// baseline (6403.163 us; speedup 1.0000x reference)
//
#include <hip/hip_runtime.h>
#include <hip/hip_bf16.h>

typedef __bf16 bf16_t;
typedef __bf16 bf16x8 __attribute__((ext_vector_type(8)));
typedef float  f32x4  __attribute__((ext_vector_type(4)));

#define EPS_LN 1e-5f
#define SCALE_ 27.712812921102035f   // sqrt(768), applied AFTER softmax

// ---------------------------------------------------------------------------
// Weight transpose + fp32->bf16 convert:  W [K][N] fp32  ->  WT [N][K] bf16
// ---------------------------------------------------------------------------
__global__ __launch_bounds__(256) void transpose_cvt(
    const float* __restrict__ W, bf16_t* __restrict__ WT, int K, int N) {
  __shared__ float tile[32][33];
  size_t mat = (size_t)blockIdx.z * (size_t)K * (size_t)N;
  int k0 = blockIdx.y * 32, n0 = blockIdx.x * 32;
  int t = threadIdx.x;
  int r = t >> 3, c4 = (t & 7) * 4;
  float4 v = *(const float4*)&W[mat + (size_t)(k0 + r) * N + n0 + c4];
  tile[r][c4 + 0] = v.x; tile[r][c4 + 1] = v.y;
  tile[r][c4 + 2] = v.z; tile[r][c4 + 3] = v.w;
  __syncthreads();
  bf16_t tmp[4];
#pragma unroll
  for (int j = 0; j < 4; j++) tmp[j] = (bf16_t)tile[c4 + j][r];
  *(ushort4*)&WT[mat + (size_t)(n0 + r) * K + k0 + c4] = *(const ushort4*)tmp;
}

// fp32 -> bf16 plain convert (x)
__global__ void cvt_x(const float* __restrict__ x, bf16_t* __restrict__ xb, int n4) {
  int i = blockIdx.x * 256 + threadIdx.x;
  if (i >= n4) return;
  float4 v = ((const float4*)x)[i];
  bf16_t tmp[4] = {(bf16_t)v.x, (bf16_t)v.y, (bf16_t)v.z, (bf16_t)v.w};
  *(ushort4*)&xb[(size_t)i * 4] = *(const ushort4*)tmp;
}

// h[b*513 + 0][e] = cls[e] + pos[0][e]
__global__ void cls_init(const float* __restrict__ cls, const float* __restrict__ pos,
                         float* __restrict__ h) {
  int i = blockIdx.x * 256 + threadIdx.x;  // 16*768
  if (i >= 16 * 768) return;
  int b = i / 768, e = i % 768;
  h[(size_t)b * 513 * 768 + e] = cls[e] + pos[e];
}

// out[b][e] = h[b*513][e]
__global__ void out_copy(const float* __restrict__ h, float* __restrict__ o) {
  int i = blockIdx.x * 256 + threadIdx.x;
  if (i >= 16 * 768) return;
  int b = i / 768, e = i % 768;
  o[i] = h[(size_t)b * 513 * 768 + e];
}

// ---------------------------------------------------------------------------
// LayerNorm: fp32 h row -> bf16 y row. One wave per row, 4 rows per block.
// ---------------------------------------------------------------------------
__global__ __launch_bounds__(256) void ln_kernel(
    const float* __restrict__ h, const float* __restrict__ g,
    const float* __restrict__ bt, bf16_t* __restrict__ y, int rows) {
  int row = blockIdx.x * 4 + (threadIdx.x >> 6);
  int lane = threadIdx.x & 63;
  if (row >= rows) return;
  const float4* x4 = (const float4*)(h + (size_t)row * 768);
  float4 v[3];
  float s = 0.f, s2 = 0.f;
#pragma unroll
  for (int i = 0; i < 3; i++) {
    v[i] = x4[lane + i * 64];
    s  += v[i].x + v[i].y + v[i].z + v[i].w;
    s2 += v[i].x * v[i].x + v[i].y * v[i].y + v[i].z * v[i].z + v[i].w * v[i].w;
  }
#pragma unroll
  for (int o = 32; o > 0; o >>= 1) {
    s  += __shfl_xor(s,  o, 64);
    s2 += __shfl_xor(s2, o, 64);
  }
  float mu  = s * (1.f / 768.f);
  float var = s2 * (1.f / 768.f) - mu * mu;
  float rs  = rsqrtf(var + EPS_LN);
  bf16_t* yr = y + (size_t)row * 768;
#pragma unroll
  for (int i = 0; i < 3; i++) {
    int c0 = (lane + i * 64) * 4;
    float e0 = (v[i].x - mu) * rs * g[c0 + 0] + bt[c0 + 0];
    float e1 = (v[i].y - mu) * rs * g[c0 + 1] + bt[c0 + 1];
    float e2 = (v[i].z - mu) * rs * g[c0 + 2] + bt[c0 + 2];
    float e3 = (v[i].w - mu) * rs * g[c0 + 3] + bt[c0 + 3];
    bf16_t tmp[4] = {(bf16_t)e0, (bf16_t)e1, (bf16_t)e2, (bf16_t)e3};
    *(ushort4*)&yr[c0] = *(const ushort4*)tmp;
  }
}

// ---------------------------------------------------------------------------
// Softmax in-place over S rows (len 513, stride 544), then /SCALE.
// Writes 0 into pad cols [513,544). One wave per row.
// ---------------------------------------------------------------------------
__global__ void softmax_kernel(bf16_t* __restrict__ S) {
  int q = blockIdx.x, z = blockIdx.y;
  bf16_t* row = S + ((size_t)z * 513 + q) * 544;
  int lane = threadIdx.x;
  float v[9];
#pragma unroll
  for (int i = 0; i < 9; i++) {
    int idx = lane + i * 64;
    v[i] = (idx < 513) ? (float)row[idx] : -1e30f;
  }
  float m = v[0];
#pragma unroll
  for (int i = 1; i < 9; i++) m = fmaxf(m, v[i]);
#pragma unroll
  for (int o = 32; o > 0; o >>= 1) m = fmaxf(m, __shfl_xor(m, o, 64));
  float s = 0.f;
#pragma unroll
  for (int i = 0; i < 9; i++) { v[i] = expf(v[i] - m); s += v[i]; }
#pragma unroll
  for (int o = 32; o > 0; o >>= 1) s += __shfl_xor(s, o, 64);
  float inv = 1.f / (s * SCALE_);
#pragma unroll
  for (int i = 0; i < 9; i++) {
    int idx = lane + i * 64;
    if (idx < 544) row[idx] = (bf16_t)((idx < 513) ? v[i] * inv : 0.f);
  }
}

// ---------------------------------------------------------------------------
// Generic bf16 MFMA GEMM:  C[M][N] = A[M][K] (lda) @ Bt[N][K] (ldb, B^T-stored)
// 256 thr = 4 waves; tile 128x128x32; wave -> 64x64 = 4x4 frags of 16x16x32.
// Epilogues (EPI):
//  0 embed: h[r + r/512 + 1][c] = acc + bias[c] + pos[(r%512+1)*768+c]   (fp32)
//  1 qkv scatter (+bias) -> q[(bh)][tok][64], k[(bh)][tok][64], vt[(bh)][64][544]
//  2 S store bf16 at S[z][r][c], stride 544
//  3 PV: o[(b*513+r)][h*64+c] bf16  (z = b*12+h)
//  4 residual: h[r][c] += acc + bias[c]      (fp32, stride 768)
//  5 ff1: gelu(acc+bias) -> ff[r][c] bf16 (stride 3072)
//  6 residual (ff2): h[r][c] += acc + bias[c]
// ---------------------------------------------------------------------------
template <int EPI>
__global__ __launch_bounds__(256) void gemm_bt(
    const bf16_t* __restrict__ A, const bf16_t* __restrict__ Bt,
    const float* __restrict__ bias,
    int M, int N, int K, int lda, int ldb,
    long long batchA, long long batchB,
    float* __restrict__ hout, const float* __restrict__ pos,
    bf16_t* __restrict__ ob,
    bf16_t* __restrict__ qb, bf16_t* __restrict__ kb, bf16_t* __restrict__ vtb) {
  __shared__ __align__(16) bf16_t As[128][40];
  __shared__ __align__(16) bf16_t Bs[128][40];
  int z = blockIdx.z;
  A  += (size_t)((long long)z * batchA);
  Bt += (size_t)((long long)z * batchB);
  int tm = blockIdx.y, tn = blockIdx.x;
  int t = threadIdx.x;
  int wave = t >> 6, lane = t & 63;
  int wr = wave >> 1, wc = wave & 1;
  int fr = lane & 15, kg = lane >> 4;

  f32x4 acc[4][4] = {};

  int arow = tm * 128 + (t >> 1);
  int brow = tn * 128 + (t >> 1);
  int arowc = arow < M ? arow : M - 1;
  int browc = brow < N ? brow : N - 1;
  int koff = (t & 1) * 16;
  const bf16_t* Ap = A + (size_t)arowc * lda + koff;
  const bf16_t* Bp = Bt + (size_t)browc * ldb + koff;
  bf16_t* asw = &As[t >> 1][koff];
  bf16_t* bsw = &Bs[t >> 1][koff];

  for (int kk = 0; kk < K; kk += 32) {
    uint4 a0 = *(const uint4*)(Ap);
    uint4 a1 = *(const uint4*)(Ap + 8);
    uint4 b0 = *(const uint4*)(Bp);
    uint4 b1 = *(const uint4*)(Bp + 8);
    Ap += 32; Bp += 32;
    __syncthreads();           // previous iter's frag reads done
    *(uint4*)(asw)     = a0;
    *(uint4*)(asw + 8) = a1;
    *(uint4*)(bsw)     = b0;
    *(uint4*)(bsw + 8) = b1;
    __syncthreads();
    bf16x8 af[4], bf[4];
#pragma unroll
    for (int m = 0; m < 4; m++)
      af[m] = *(const bf16x8*)&As[wr * 64 + m * 16 + fr][kg * 8];
#pragma unroll
    for (int n = 0; n < 4; n++)
      bf[n] = *(const bf16x8*)&Bs[wc * 64 + n * 16 + fr][kg * 8];
#pragma unroll
    for (int m = 0; m < 4; m++)
#pragma unroll
      for (int n = 0; n < 4; n++)
        acc[m][n] = __builtin_amdgcn_mfma_f32_16x16x32_bf16(af[m], bf[n], acc[m][n], 0, 0, 0);
  }

  int brow0 = tm * 128 + wr * 64;
  int bcol0 = tn * 128 + wc * 64;
#pragma unroll
  for (int m = 0; m < 4; m++) {
#pragma unroll
    for (int n = 0; n < 4; n++) {
#pragma unroll
      for (int j = 0; j < 4; j++) {
        int r = brow0 + m * 16 + kg * 4 + j;
        int c = bcol0 + n * 16 + fr;
        if (r >= M || c >= N) continue;
        float v = acc[m][n][j];
        if (EPI == 0) {
          int b = r >> 9;
          int hrow = r + b + 1;
          int nn = r & 511;
          hout[(size_t)hrow * 768 + c] = v + bias[c] + pos[(size_t)(nn + 1) * 768 + c];
        } else if (EPI == 1) {
          float val = v + bias[c];
          int b = r / 513, tok = r - b * 513;
          int hh = c / 192, rem = c - hh * 192, d = rem / 3, which = rem - d * 3;
          size_t zz = (size_t)(b * 12 + hh);
          if (which == 0)      qb[(zz * 513 + tok) * 64 + d] = (bf16_t)val;
          else if (which == 1) kb[(zz * 513 + tok) * 64 + d] = (bf16_t)val;
          else                 vtb[(zz * 64 + d) * 544 + tok] = (bf16_t)val;
        } else if (EPI == 2) {
          ob[((size_t)z * 513 + r) * 544 + c] = (bf16_t)v;
        } else if (EPI == 3) {
          int b = z / 12, hh = z - b * 12;
          ob[((size_t)(b * 513 + r)) * 768 + hh * 64 + c] = (bf16_t)v;
        } else if (EPI == 4 || EPI == 6) {
          float* p = &hout[(size_t)r * 768 + c];
          *p = *p + v + bias[c];
        } else if (EPI == 5) {
          float u = v + bias[c];
          float gl = 0.5f * u * (1.0f + erff(u * 0.70710678118654752f));
          ob[(size_t)r * 3072 + c] = (bf16_t)gl;
        }
      }
    }
  }
}

// ---------------------------------------------------------------------------
extern "C" void kernel_launch(void* const* d_in, const int* in_sizes, int n_in,
                              void* d_out, int out_size, void* d_ws, size_t ws_size,
                              hipStream_t stream) {
  const float* x      = (const float*)d_in[0];
  const float* proj_w = (const float*)d_in[1];
  const float* proj_b = (const float*)d_in[2];
  const float* cls    = (const float*)d_in[3];
  const float* pos    = (const float*)d_in[4];
  const float* ln1_g  = (const float*)d_in[5];
  const float* ln1_b  = (const float*)d_in[6];
  const float* qkv_w  = (const float*)d_in[7];
  const float* qkv_b  = (const float*)d_in[8];
  const float* out_w  = (const float*)d_in[9];
  const float* out_b  = (const float*)d_in[10];
  const float* ln2_g  = (const float*)d_in[11];
  const float* ln2_b  = (const float*)d_in[12];
  const float* ff1_w  = (const float*)d_in[13];
  const float* ff1_b  = (const float*)d_in[14];
  const float* ff2_w  = (const float*)d_in[15];
  const float* ff2_b  = (const float*)d_in[16];
  float* outp = (float*)d_out;

  char* ws = (char*)d_ws;
  size_t off = 0;
  auto alloc = [&](size_t bytes) {
    char* p = ws + off;
    off += (bytes + 255) & ~(size_t)255;
    return p;
  };
  bf16_t* wt_proj = (bf16_t*)alloc((size_t)768 * 768 * 2);
  bf16_t* wt_qkv  = (bf16_t*)alloc((size_t)12 * 2304 * 768 * 2);
  bf16_t* wt_out  = (bf16_t*)alloc((size_t)12 * 768 * 768 * 2);
  bf16_t* wt_ff1  = (bf16_t*)alloc((size_t)12 * 3072 * 768 * 2);
  bf16_t* wt_ff2  = (bf16_t*)alloc((size_t)12 * 768 * 3072 * 2);
  bf16_t* xb      = (bf16_t*)alloc((size_t)8192 * 768 * 2);
  float*  h       = (float*) alloc((size_t)8208 * 768 * 4);
  bf16_t* y       = (bf16_t*)alloc((size_t)8208 * 768 * 2);
  bf16_t* qb      = (bf16_t*)alloc((size_t)192 * 513 * 64 * 2);
  bf16_t* kb      = (bf16_t*)alloc((size_t)192 * 513 * 64 * 2);
  bf16_t* vt      = (bf16_t*)alloc((size_t)192 * 64 * 544 * 2);
  bf16_t* S       = (bf16_t*)alloc((size_t)192 * 513 * 544 * 2);
  bf16_t* o       = (bf16_t*)alloc((size_t)8208 * 768 * 2);
  bf16_t* ff      = (bf16_t*)alloc((size_t)8208 * 3072 * 2);
  (void)ws_size; (void)n_in; (void)in_sizes; (void)out_size;

  // ---- weight prep (every call: ws is re-poisoned between launches) ----
  transpose_cvt<<<dim3(768 / 32, 768 / 32, 1),  256, 0, stream>>>(proj_w, wt_proj, 768, 768);
  transpose_cvt<<<dim3(2304 / 32, 768 / 32, 12), 256, 0, stream>>>(qkv_w, wt_qkv, 768, 2304);
  transpose_cvt<<<dim3(768 / 32, 768 / 32, 12),  256, 0, stream>>>(out_w, wt_out, 768, 768);
  transpose_cvt<<<dim3(3072 / 32, 768 / 32, 12), 256, 0, stream>>>(ff1_w, wt_ff1, 768, 3072);
  transpose_cvt<<<dim3(768 / 32, 3072 / 32, 12), 256, 0, stream>>>(ff2_w, wt_ff2, 3072, 768);
  cvt_x<<<6144, 256, 0, stream>>>(x, xb, 8192 * 768 / 4);

  // ---- embed: h = [cls; x@proj_w + proj_b] + pos ----
  gemm_bt<0><<<dim3(6, 64, 1), 256, 0, stream>>>(
      xb, wt_proj, proj_b, 8192, 768, 768, 768, 768, 0, 0,
      h, pos, nullptr, nullptr, nullptr, nullptr);
  cls_init<<<48, 256, 0, stream>>>(cls, pos, h);

  for (int l = 0; l < 12; l++) {
    const bf16_t* wq = wt_qkv + (size_t)l * 2304 * 768;
    const bf16_t* wo = wt_out + (size_t)l * 768 * 768;
    const bf16_t* w1 = wt_ff1 + (size_t)l * 3072 * 768;
    const bf16_t* w2 = wt_ff2 + (size_t)l * 768 * 3072;

    ln_kernel<<<2052, 256, 0, stream>>>(h, ln1_g + l * 768, ln1_b + l * 768, y, 8208);

    gemm_bt<1><<<dim3(18, 65, 1), 256, 0, stream>>>(
        y, wq, qkv_b + l * 2304, 8208, 2304, 768, 768, 768, 0, 0,
        nullptr, nullptr, nullptr, qb, kb, vt);

    gemm_bt<2><<<dim3(5, 5, 192), 256, 0, stream>>>(
        qb, kb, nullptr, 513, 513, 64, 64, 64,
        (long long)513 * 64, (long long)513 * 64,
        nullptr, nullptr, S, nullptr, nullptr, nullptr);

    softmax_kernel<<<dim3(513, 192), 64, 0, stream>>>(S);

    gemm_bt<3><<<dim3(1, 5, 192), 256, 0, stream>>>(
        S, vt, nullptr, 513, 64, 544, 544, 544,
        (long long)513 * 544, (long long)64 * 544,
        nullptr, nullptr, o, nullptr, nullptr, nullptr);

    gemm_bt<4><<<dim3(6, 65, 1), 256, 0, stream>>>(
        o, wo, out_b + l * 768, 8208, 768, 768, 768, 768, 0, 0,
        h, nullptr, nullptr, nullptr, nullptr, nullptr);

    ln_kernel<<<2052, 256, 0, stream>>>(h, ln2_g + l * 768, ln2_b + l * 768, y, 8208);

    gemm_bt<5><<<dim3(24, 65, 1), 256, 0, stream>>>(
        y, w1, ff1_b + l * 3072, 8208, 3072, 768, 768, 768, 0, 0,
        nullptr, nullptr, ff, nullptr, nullptr, nullptr);

    gemm_bt<6><<<dim3(6, 65, 1), 256, 0, stream>>>(
        ff, w2, ff2_b + l * 768, 8208, 768, 3072, 3072, 3072, 0, 0,
        h, nullptr, nullptr, nullptr, nullptr, nullptr);
  }

  out_copy<<<48, 256, 0, stream>>>(h, outp);
}